// Round 1
// baseline (522.553 us; speedup 1.0000x reference)
//
#include <hip/hip_runtime.h>

// WeightController: PI-style integral update + history-buffer shift.
//
// Outputs (concatenated flat in d_out, fp32):
//   [0 : 2048)                       weight_state_next
//   [2048 : 2048 + 8000*2048*5)      recording_next (history, batch, vars)
//
// recording_next[t] = recording[t+1] for t in [0, 7999)   <- bulk D2D copy, ~328 MB
// recording_next[7999, i, :] = (cv, ws_next, to_int, rl, e)  <- tiny kernel
//
// Memory-bound: ~655 MB total HBM traffic -> ~104 us floor at 6.3 TB/s.

#define N_BATCH     2048
#define N_HISTORY   8000
#define N_VARS      5
#define REF_V       (-0.2f)
#define K_I_V       (4.0f)
#define RATE_MAX_V  (0.01f)
#define RATE_MIN_V  (-0.02f)
#define LAMBDA_V    (1.5f)

__global__ __launch_bounds__(256) void wc_update_kernel(
    const float* __restrict__ cv,
    const float* __restrict__ ws,
    float* __restrict__ out) {
    int i = blockIdx.x * blockDim.x + threadIdx.x;
    if (i >= N_BATCH) return;

    float c      = cv[i];
    float e      = REF_V - c;
    float to_int = K_I_V * e;
    float rl     = fminf(fmaxf(to_int, RATE_MIN_V), RATE_MAX_V);
    float wn     = fminf(fmaxf(ws[i] + rl, 0.0f), LAMBDA_V);

    // Output 0: weight_state_next
    out[i] = wn;

    // Last history row of recording_next: (cv, ws_next, to_int, rl, e)
    float* rec = out + N_BATCH
               + (size_t)(N_HISTORY - 1) * N_BATCH * N_VARS
               + (size_t)i * N_VARS;
    rec[0] = c;
    rec[1] = wn;
    rec[2] = to_int;
    rec[3] = rl;
    rec[4] = e;
}

extern "C" void kernel_launch(void* const* d_in, const int* in_sizes, int n_in,
                              void* d_out, int out_size, void* d_ws, size_t ws_size,
                              hipStream_t stream) {
    const float* cv  = (const float*)d_in[0];   // controlled_variable (2048,)
    const float* ws  = (const float*)d_in[1];   // weight_state (2048,)
    const float* rec = (const float*)d_in[2];   // recording (8000, 2048, 5)
    float* out = (float*)d_out;

    // Bulk shift: recording[1:] -> recording_next[:7999]
    const size_t row_elems  = (size_t)N_BATCH * N_VARS;             // 10240
    const size_t copy_elems = (size_t)(N_HISTORY - 1) * row_elems;  // 81,909,760
    hipMemcpyAsync(out + N_BATCH,            // dst: recording_next row 0
                   rec + row_elems,          // src: recording row 1
                   copy_elems * sizeof(float),
                   hipMemcpyDeviceToDevice, stream);

    // Controller update + last record row (tiny)
    wc_update_kernel<<<(N_BATCH + 255) / 256, 256, 0, stream>>>(cv, ws, out);
}